// Round 9
// baseline (641.402 us; speedup 1.0000x reference)
//
#include <hip/hip_runtime.h>
#include <stdint.h>

#define NB 8
#define NT 1024
#define ND 768
#define NV 768
#define NL 13
#define MTOK (NB*NT)          // 8192
#define MROWS (MTOK*NL)       // 106496

typedef __attribute__((ext_vector_type(8))) short short8;
typedef __attribute__((ext_vector_type(4))) float f32x4;

__device__ __forceinline__ unsigned short f2bf(float f) {
    union { float f; unsigned u; } v; v.f = f;
    unsigned r = v.u + 0x7FFFu + ((v.u >> 16) & 1u);
    return (unsigned short)(r >> 16);
}
__device__ __forceinline__ float bf2f(unsigned short u) {
    union { unsigned u; float f; } v; v.u = ((unsigned)u) << 16;
    return v.f;
}
__device__ __forceinline__ unsigned cvtpk(float lo, float hi) {
    unsigned r;
    asm("v_cvt_pk_bf16_f32 %0, %1, %2" : "=v"(r) : "v"(lo), "v"(hi));
    return r;
}
__device__ __forceinline__ void gload16(const void* g, void* l) {
    __builtin_amdgcn_global_load_lds(
        (const __attribute__((address_space(1))) unsigned int*)g,
        (__attribute__((address_space(3))) unsigned int*)l, 16, 0, 0);
}

// ---------------------------------------------------------------------------
// fp32 -> bf16 bulk convert (weights only)
// ---------------------------------------------------------------------------
__global__ __launch_bounds__(256) void conv_f32_bf16(
    const float* __restrict__ s, unsigned short* __restrict__ d, long n)
{
    long i = ((long)blockIdx.x * 256 + threadIdx.x) * 8;
    long st = (long)gridDim.x * 2048;
    for (; i < n; i += st) {
        float4 a = *(const float4*)(s + i);
        float4 b = *(const float4*)(s + i + 4);
        ushort4 u0, u1;
        u0.x = f2bf(a.x); u0.y = f2bf(a.y); u0.z = f2bf(a.z); u0.w = f2bf(a.w);
        u1.x = f2bf(b.x); u1.y = f2bf(b.y); u1.z = f2bf(b.z); u1.w = f2bf(b.w);
        *(ushort4*)(d + i)     = u0;
        *(ushort4*)(d + i + 4) = u1;
    }
}

// ---------------------------------------------------------------------------
// GEMM1: C(bf16) = A(fp32) * B(bf16)^T + bias.  K=768, BK=64 (12 tiles).
// XCD-grouped grid (8 x 104 x 6 = 4992).  Per tile: issue A reg-loads + B
// gloads EARLY, 32-MFMA COMP (2 sub-phases of K=32) hides the latency, then
// cvt+ds_write A and ONE barrier.  A LDS rows padded to 44 ushorts
// (22*lr mod 32 = full period -> conflict-free ds_read_b128).
// ---------------------------------------------------------------------------
__global__ __launch_bounds__(256) void gemm_f32a(
    const float* __restrict__ A, const unsigned short* __restrict__ B,
    const float* __restrict__ biasBase, unsigned short* __restrict__ C,
    long aLS, long bLS, int biasLS, long cLayerOff, long cRowStride)
{
    __shared__ __align__(16) unsigned short lsA[2][2][128 * 44]; // [buf][khalf]
    __shared__ __align__(16) unsigned short lsB[2][2][4096];     // [buf][khalf]

    const int bid = blockIdx.x;
    const int xcd = bid & 7, slot = bid >> 3;        // 624 slots per XCD
    const int grp = xcd * 104 + slot / 6;
    const int nx  = slot % 6;
    const int l   = grp >> 6;                        // layer 0..12
    const long m0 = (long)(grp & 63) * 128;
    const long n0 = (long)nx * 128;

    const int t = threadIdx.x, lane = t & 63, wave = t >> 6;

    const float* Ab = A + (size_t)l * aLS;
    const unsigned short* Bb = B + (size_t)l * bLS;
    const float* bias = biasBase + (size_t)l * biasLS;

    // A reg staging: thread covers row t>>1, k-half t&1 (32 floats = 8 f32x4)
    const int aRow  = t >> 1;
    const int aHalf = t & 1;
    const float* aSrc = Ab + (m0 + aRow) * (size_t)768 + aHalf * 32;

    // B gload staging (verified R5/R6/R8): linear dest, XOR source chunk
    const int brow = wave * 16 + (lane >> 2);
    const int bchk = (lane & 3) ^ ((lane >> 3) & 3);
    const int dB   = wave * 1024 + lane * 16;
    const unsigned short* bSp0 = Bb + (n0 + brow) * (size_t)768 + bchk * 8;
    const unsigned short* bSp1 = Bb + (n0 + 64 + brow) * (size_t)768 + bchk * 8;

    const int wm = (wave >> 1) * 64;
    const int wn = (wave & 1) * 64;
    const int lr = lane & 15;
    const int g4 = lane >> 4;
    const int kg = g4 * 8;
    const int swzB = ((lr >> 1) & 3) * 8;

    f32x4 acc[4][4];
#pragma unroll
    for (int i = 0; i < 4; i++)
#pragma unroll
        for (int j = 0; j < 4; j++) acc[i][j] = (f32x4){0.f, 0.f, 0.f, 0.f};

    f32x4 areg[8];

    auto LOADA = [&](int k0) {
#pragma unroll
        for (int i = 0; i < 8; i++)
            areg[i] = *(const f32x4*)(aSrc + k0 + i * 4);
    };
    auto WRITEA = [&](int buf) {
        unsigned short* la = lsA[buf][aHalf];
#pragma unroll
        for (int i = 0; i < 8; i++) {
            uint2 w;
            w.x = cvtpk(areg[i][0], areg[i][1]);
            w.y = cvtpk(areg[i][2], areg[i][3]);
            *(uint2*)&la[aRow * 44 + i * 4] = w;
        }
    };
    auto STAGEB = [&](int buf, int k0) {
#pragma unroll
        for (int h = 0; h < 2; h++) {
            char* lb = (char*)lsB[buf][h];
            gload16(bSp0 + k0 + h * 32, lb + dB);
            gload16(bSp1 + k0 + h * 32, lb + 4096 + dB);
        }
    };
    auto COMP = [&](int buf) {
#pragma unroll
        for (int kk = 0; kk < 2; kk++) {
            short8 af[4], bv[4];
            const unsigned short* pa = lsA[buf][kk];
            const unsigned short* pb = lsB[buf][kk];
#pragma unroll
            for (int mi = 0; mi < 4; mi++)
                af[mi] = *(const short8*)&pa[(wm + mi * 16 + lr) * 44 + kg];
#pragma unroll
            for (int ni = 0; ni < 4; ni++)
                bv[ni] = *(const short8*)&pb[(wn + ni * 16 + lr) * 32 + (kg ^ swzB)];
#pragma unroll
            for (int mi = 0; mi < 4; mi++)
#pragma unroll
                for (int ni = 0; ni < 4; ni++)
                    acc[mi][ni] = __builtin_amdgcn_mfma_f32_16x16x32_bf16(
                        af[mi], bv[ni], acc[mi][ni], 0, 0, 0);
        }
    };

    // Prologue: tile0 regs + gloads, write, barrier (full drain covers B0).
    LOADA(0);
    STAGEB(0, 0);
    WRITEA(0);
    __syncthreads();

    int cur = 0;
    for (int ks = 1; ks < 12; ks++) {
        LOADA(ks * 64);            // next A tile -> regs (in flight over COMP)
        STAGEB(cur ^ 1, ks * 64);  // next B tile -> LDS direct
        COMP(cur);                 // 32 MFMA: covers ~HBM latency
        WRITEA(cur ^ 1);           // compiler waits only the 8 areg loads
        __syncthreads();           // drains B gloads (issued pre-COMP)
        cur ^= 1;
    }
    COMP(cur);

#pragma unroll
    for (int ni = 0; ni < 4; ni++) {
        long col = n0 + wn + ni * 16 + lr;
        float bvs = bias[col];
#pragma unroll
        for (int mi = 0; mi < 4; mi++) {
#pragma unroll
            for (int r = 0; r < 4; r++) {
                long grow = m0 + wm + mi * 16 + (lane >> 4) * 4 + r;
                size_t coff = (size_t)grow * cRowStride + (size_t)l * cLayerOff + col;
                C[coff] = f2bf(acc[mi][ni][r] + bvs);
            }
        }
    }
}

// ---------------------------------------------------------------------------
// GEMM2: C(f32) = A(bf16) * B(bf16)^T + bias.  K=3072, BK=64 (48 tiles),
// pure gload staging, one barrier per tile.  grid = 384.
// ---------------------------------------------------------------------------
__global__ __launch_bounds__(256) void gemm_bf16_nt(
    const unsigned short* __restrict__ A, const unsigned short* __restrict__ B,
    const float* __restrict__ bias, float* __restrict__ C,
    int K, long cRowStride)
{
    __shared__ __align__(16) unsigned short lsA[2][2][4096];
    __shared__ __align__(16) unsigned short lsB[2][2][4096];

    const int bid = blockIdx.x;
    const int xcd = bid & 7, slot = bid >> 3;        // 48 slots per XCD
    const int grp = xcd * 8 + slot / 6;              // 0..63
    const int nx  = slot % 6;
    const long m0 = (long)grp * 128;
    const long n0 = (long)nx * 128;

    const int t = threadIdx.x, lane = t & 63, wave = t >> 6;

    const int brow = wave * 16 + (lane >> 2);
    const int bchk = (lane & 3) ^ ((lane >> 3) & 3);
    const int dA   = wave * 1024 + lane * 16;

    const int wm = (wave >> 1) * 64;
    const int wn = (wave & 1) * 64;
    const int lr = lane & 15;
    const int g4 = lane >> 4;
    const int kg = g4 * 8;
    const int swz = ((lr >> 1) & 3) * 8;

    const unsigned short* aSp0 = A + (m0 + brow) * (size_t)K + bchk * 8;
    const unsigned short* aSp1 = A + (m0 + 64 + brow) * (size_t)K + bchk * 8;
    const unsigned short* bSp0 = B + (n0 + brow) * (size_t)K + bchk * 8;
    const unsigned short* bSp1 = B + (n0 + 64 + brow) * (size_t)K + bchk * 8;

    f32x4 acc[4][4];
#pragma unroll
    for (int i = 0; i < 4; i++)
#pragma unroll
        for (int j = 0; j < 4; j++) acc[i][j] = (f32x4){0.f, 0.f, 0.f, 0.f};

    auto STAGE = [&](int buf, int k0) {
#pragma unroll
        for (int h = 0; h < 2; h++) {
            char* la = (char*)lsA[buf][h];
            char* lb = (char*)lsB[buf][h];
            gload16(aSp0 + k0 + h * 32, la + dA);
            gload16(aSp1 + k0 + h * 32, la + 4096 + dA);
            gload16(bSp0 + k0 + h * 32, lb + dA);
            gload16(bSp1 + k0 + h * 32, lb + 4096 + dA);
        }
    };
    auto COMP = [&](int buf) {
#pragma unroll
        for (int kk = 0; kk < 2; kk++) {
            short8 af[4], bv[4];
            const unsigned short* pa = lsA[buf][kk];
            const unsigned short* pb = lsB[buf][kk];
#pragma unroll
            for (int mi = 0; mi < 4; mi++)
                af[mi] = *(const short8*)&pa[(wm + mi * 16 + lr) * 32 + (kg ^ swz)];
#pragma unroll
            for (int ni = 0; ni < 4; ni++)
                bv[ni] = *(const short8*)&pb[(wn + ni * 16 + lr) * 32 + (kg ^ swz)];
#pragma unroll
            for (int mi = 0; mi < 4; mi++)
#pragma unroll
                for (int ni = 0; ni < 4; ni++)
                    acc[mi][ni] = __builtin_amdgcn_mfma_f32_16x16x32_bf16(
                        af[mi], bv[ni], acc[mi][ni], 0, 0, 0);
        }
    };

    STAGE(0, 0);
    __syncthreads();
    int cur = 0;
    const int nst = K >> 6;
    for (int ks = 1; ks < nst; ks++) {
        STAGE(cur ^ 1, ks * 64);
        COMP(cur);
        __syncthreads();
        cur ^= 1;
    }
    COMP(cur);

#pragma unroll
    for (int ni = 0; ni < 4; ni++) {
        long col = n0 + wn + ni * 16 + lr;
        float bvs = bias[col];
#pragma unroll
        for (int mi = 0; mi < 4; mi++) {
#pragma unroll
            for (int r = 0; r < 4; r++) {
                long grow = m0 + wm + mi * 16 + (lane >> 4) * 4 + r;
                C[(size_t)grow * cRowStride + col] = acc[mi][ni][r] + bvs;
            }
        }
    }
}

// ---------------------------------------------------------------------------
// Fold kvln gamma into k_w; compute s_k = sum(kw*g), c_k = kw.b + k_bias.
// ---------------------------------------------------------------------------
__global__ __launch_bounds__(256) void wtrans(
    const float* __restrict__ kw, const float* __restrict__ kvg,
    const float* __restrict__ kvb, const float* __restrict__ kbias,
    float* __restrict__ kwp, float* __restrict__ skv, float* __restrict__ ckv)
{
    __shared__ float red[8];
    const int q = blockIdx.x, t = threadIdx.x;
    const int lane = t & 63, wave = t >> 6;
    float s = 0.f, c = 0.f;
    for (int v = t; v < 768; v += 256) {
        float w = kw[q * 768 + v];
        float wp = w * kvg[v];
        kwp[q * 768 + v] = wp;
        s += wp;
        c += w * kvb[v];
    }
#pragma unroll
    for (int off = 1; off < 64; off <<= 1) {
        s += __shfl_xor(s, off);
        c += __shfl_xor(c, off);
    }
    if (lane == 0) { red[wave] = s; red[4 + wave] = c; }
    __syncthreads();
    if (t == 0) {
        skv[q] = red[0] + red[1] + red[2] + red[3];
        ckv[q] = red[4] + red[5] + red[6] + red[7] + kbias[q];
    }
}

// ---------------------------------------------------------------------------
// LayerNorm rows of 768 (fp32 src) -> bf16.  Q side only.
// ---------------------------------------------------------------------------
__global__ __launch_bounds__(256) void ln_rows_f32(
    const float* __restrict__ src, unsigned short* __restrict__ dst,
    const float* __restrict__ gam, const float* __restrict__ bet)
{
    const int lane = threadIdx.x & 63;
    const int wave = threadIdx.x >> 6;
    const size_t row = (size_t)blockIdx.x * 4 + wave;

    float x[3][4];
    float s = 0.f, sq = 0.f;
#pragma unroll
    for (int i = 0; i < 3; i++) {
        int v = i * 256 + lane * 4;
        float4 f = *(const float4*)(src + row * 768 + v);
        x[i][0] = f.x; x[i][1] = f.y; x[i][2] = f.z; x[i][3] = f.w;
#pragma unroll
        for (int e = 0; e < 4; e++) { s += x[i][e]; sq += x[i][e] * x[i][e]; }
    }
#pragma unroll
    for (int off = 1; off < 64; off <<= 1) {
        s  += __shfl_xor(s, off);
        sq += __shfl_xor(sq, off);
    }
    float mean = s * (1.f / 768.f);
    float var  = sq * (1.f / 768.f) - mean * mean;
    float rs   = rsqrtf(var + 1e-5f);
#pragma unroll
    for (int i = 0; i < 3; i++) {
        int v = i * 256 + lane * 4;
        float4 gg = *(const float4*)(gam + v);
        float4 bb = *(const float4*)(bet + v);
        ushort4 o;
        o.x = f2bf((x[i][0] - mean) * rs * gg.x + bb.x);
        o.y = f2bf((x[i][1] - mean) * rs * gg.y + bb.y);
        o.z = f2bf((x[i][2] - mean) * rs * gg.z + bb.z);
        o.w = f2bf((x[i][3] - mean) * rs * gg.w + bb.w);
        *(ushort4*)(dst + row * 768 + v) = o;
    }
}

// ---------------------------------------------------------------------------
// proj32: out[M][32] = A[M][768](bf16) @ W[32][768](f32)^T + bias (plain).
// ---------------------------------------------------------------------------
__global__ __launch_bounds__(256) void proj32(
    const unsigned short* __restrict__ A, const float* __restrict__ W,
    const float* __restrict__ bias, unsigned short* __restrict__ out)
{
    __shared__ __align__(16) unsigned short lsW[32 * 776];
    __shared__ __align__(16) unsigned short lsA[128 * 40];
    const int t = threadIdx.x;

#pragma unroll
    for (int i = 0; i < 24; i++) {
        int fi = t + i * 256;
        int row = fi / 192;
        int c4  = fi % 192;
        float4 f = *(const float4*)(W + row * 768 + c4 * 4);
        ushort4 u;
        u.x = f2bf(f.x); u.y = f2bf(f.y); u.z = f2bf(f.z); u.w = f2bf(f.w);
        *(ushort4*)&lsW[row * 776 + c4 * 4] = u;
    }

    const size_t m0 = (size_t)blockIdx.x * 128;
    const int lane = t & 63, wave = t >> 6;
    const int wm = wave * 32;
    const int lr = lane & 15, kg = (lane >> 4) * 8;
    const int row_s = t >> 3, c4s = t & 7;

    f32x4 acc[2][2];
#pragma unroll
    for (int i = 0; i < 2; i++)
#pragma unroll
        for (int j = 0; j < 2; j++) acc[i][j] = (f32x4){0.f, 0.f, 0.f, 0.f};

    __syncthreads();

    for (int k0 = 0; k0 < 768; k0 += 32) {
#pragma unroll
        for (int i = 0; i < 4; i++) {
            int row = row_s + 32 * i;
            ushort4 v = *(const ushort4*)(A + (m0 + row) * 768 + k0 + c4s * 4);
            *(ushort4*)&lsA[row * 40 + c4s * 4] = v;
        }
        __syncthreads();
        short8 af[2], bw[2];
#pragma unroll
        for (int mi = 0; mi < 2; mi++)
            af[mi] = *(const short8*)&lsA[(wm + mi * 16 + lr) * 40 + kg];
#pragma unroll
        for (int ni = 0; ni < 2; ni++)
            bw[ni] = *(const short8*)&lsW[(ni * 16 + lr) * 776 + k0 + kg];
#pragma unroll
        for (int mi = 0; mi < 2; mi++)
#pragma unroll
            for (int ni = 0; ni < 2; ni++)
                acc[mi][ni] = __builtin_amdgcn_mfma_f32_16x16x32_bf16(
                    af[mi], bw[ni], acc[mi][ni], 0, 0, 0);
        __syncthreads();
    }

#pragma unroll
    for (int ni = 0; ni < 2; ni++) {
        int col = ni * 16 + lr;
        float bv = bias[col];
#pragma unroll
        for (int mi = 0; mi < 2; mi++) {
#pragma unroll
            for (int r = 0; r < 4; r++) {
                size_t grow = m0 + wm + mi * 16 + (lane >> 4) * 4 + r;
                out[grow * 32 + col] = f2bf(acc[mi][ni][r] + bv);
            }
        }
    }
}

// ---------------------------------------------------------------------------
// proj32k_stats: k = rs*(dot(x_raw, kwp) - mean*s_k) + c_k, with row stats
// computed in the K-loop.
// ---------------------------------------------------------------------------
__global__ __launch_bounds__(256) void proj32k_stats(
    const unsigned short* __restrict__ A, const float* __restrict__ W,
    const float* __restrict__ skv, const float* __restrict__ ckv,
    unsigned short* __restrict__ out, float2* __restrict__ st)
{
    __shared__ __align__(16) unsigned short lsW[32 * 776];
    __shared__ __align__(16) unsigned short lsA[128 * 40];
    __shared__ float2 lstat[128];
    const int t = threadIdx.x;

#pragma unroll
    for (int i = 0; i < 24; i++) {
        int fi = t + i * 256;
        int row = fi / 192;
        int c4  = fi % 192;
        float4 f = *(const float4*)(W + row * 768 + c4 * 4);
        ushort4 u;
        u.x = f2bf(f.x); u.y = f2bf(f.y); u.z = f2bf(f.z); u.w = f2bf(f.w);
        *(ushort4*)&lsW[row * 776 + c4 * 4] = u;
    }

    const size_t m0 = (size_t)blockIdx.x * 128;
    const int lane = t & 63, wave = t >> 6;
    const int wm = wave * 32;
    const int lr = lane & 15, kg = (lane >> 4) * 8;
    const int row_s = t >> 3, c4s = t & 7;

    f32x4 acc[2][2];
#pragma unroll
    for (int i = 0; i < 2; i++)
#pragma unroll
        for (int j = 0; j < 2; j++) acc[i][j] = (f32x4){0.f, 0.f, 0.f, 0.f};

    float s_[4] = {0.f, 0.f, 0.f, 0.f}, sq_[4] = {0.f, 0.f, 0.f, 0.f};

    __syncthreads();

    for (int k0 = 0; k0 < 768; k0 += 32) {
#pragma unroll
        for (int i = 0; i < 4; i++) {
            int row = row_s + 32 * i;
            ushort4 v = *(const ushort4*)(A + (m0 + row) * 768 + k0 + c4s * 4);
            *(ushort4*)&lsA[row * 40 + c4s * 4] = v;
            float x0 = bf2f(v.x), x1 = bf2f(v.y), x2 = bf2f(v.z), x3 = bf2f(v.w);
            s_[i]  += x0 + x1 + x2 + x3;
            sq_[i] += x0 * x0 + x1 * x1 + x2 * x2 + x3 * x3;
        }
        __syncthreads();
        short8 af[2], bw[2];
#pragma unroll
        for (int mi = 0; mi < 2; mi++)
            af[mi] = *(const short8*)&lsA[(wm + mi * 16 + lr) * 40 + kg];
#pragma unroll
        for (int ni = 0; ni < 2; ni++)
            bw[ni] = *(const short8*)&lsW[(ni * 16 + lr) * 776 + k0 + kg];
#pragma unroll
        for (int mi = 0; mi < 2; mi++)
#pragma unroll
            for (int ni = 0; ni < 2; ni++)
                acc[mi][ni] = __builtin_amdgcn_mfma_f32_16x16x32_bf16(
                    af[mi], bw[ni], acc[mi][ni], 0, 0, 0);
        __syncthreads();
    }

#pragma unroll
    for (int i = 0; i < 4; i++) {
#pragma unroll
        for (int off = 1; off < 8; off <<= 1) {
            s_[i]  += __shfl_xor(s_[i], off);
            sq_[i] += __shfl_xor(sq_[i], off);
        }
    }
    if (c4s == 0) {
#pragma unroll
        for (int i = 0; i < 4; i++) {
            int row = row_s + 32 * i;
            float mean = s_[i] * (1.f / 768.f);
            float var  = sq_[i] * (1.f / 768.f) - mean * mean;
            float2 sv = make_float2(mean, rsqrtf(var + 1e-5f));
            lstat[row] = sv;
            st[m0 + row] = sv;
        }
    }
    __syncthreads();

#pragma unroll
    for (int ni = 0; ni < 2; ni++) {
        int col = ni * 16 + lr;
        float sk = skv[col], ck = ckv[col];
#pragma unroll
        for (int mi = 0; mi < 2; mi++) {
#pragma unroll
            for (int r = 0; r < 4; r++) {
                int lrow = wm + mi * 16 + (lane >> 4) * 4 + r;
                float2 s2 = lstat[lrow];
                out[(m0 + lrow) * 32 + col] =
                    f2bf(s2.y * (acc[mi][ni][r] - s2.x * sk) + ck);
            }
        }
    }
}

// ---------------------------------------------------------------------------
// Attention on RAW aligned values with LN folded in.  One wave per token.
// ---------------------------------------------------------------------------
__global__ __launch_bounds__(256) void attn2(
    const unsigned short* __restrict__ qb, const unsigned short* __restrict__ kb,
    const unsigned short* __restrict__ kv, const float2* __restrict__ st,
    const float* __restrict__ gv, const float* __restrict__ bvv,
    unsigned short* __restrict__ oh)
{
    __shared__ float lat[4][4][13];
    __shared__ float latc[4][4];
    const int t = threadIdx.x, lane = t & 63, wave = t >> 6;
    const size_t m = (size_t)blockIdx.x * 4 + wave;

    if (lane < 32) {
        int j = lane;
        float qv = bf2f(qb[m * 32 + j]);
        float p[13];
#pragma unroll
        for (int l = 0; l < 13; l++)
            p[l] = qv * bf2f(kb[(m * 13 + l) * 32 + j]);
#pragma unroll
        for (int off = 1; off < 8; off <<= 1)
#pragma unroll
            for (int l = 0; l < 13; l++) p[l] += __shfl_xor(p[l], off);

        const float sc = 0.17677669529663687f; // 1 / (sqrt(8) * 2)
        float mx = -1e30f;
#pragma unroll
        for (int l = 0; l < 13; l++) { p[l] *= sc; mx = fmaxf(mx, p[l]); }
        float se = 0.f;
#pragma unroll
        for (int l = 0; l < 13; l++) { p[l] = __expf(p[l] - mx); se += p[l]; }
        float inv = 1.f / se;
        if ((j & 7) == 0) {
            int h = j >> 3;
            float corr = 0.f;
#pragma unroll
            for (int l = 0; l < 13; l++) {
                float2 s_ = st[m * 13 + l];
                float wl = p[l] * inv * s_.y;
                lat[wave][h][l] = wl;
                corr += wl * s_.x;
            }
            latc[wave][h] = corr;
        }
    }
    __syncthreads();

    f32x4 g4v[3], b4[3];
#pragma unroll
    for (int i = 0; i < 3; i++) {
        g4v[i] = *(const f32x4*)(gv + i * 256 + lane * 4);
        b4[i] = *(const f32x4*)(bvv + i * 256 + lane * 4);
    }

    float acc[4][3][4];
#pragma unroll
    for (int h = 0; h < 4; h++)
#pragma unroll
        for (int i = 0; i < 3; i++)
#pragma unroll
            for (int e = 0; e < 4; e++) acc[h][i][e] = 0.f;

    for (int l = 0; l < 13; l++) {
        float al[4];
#pragma unroll
        for (int h = 0; h < 4; h++) al[h] = lat[wave][h][l];
#pragma unroll
        for (int i = 0; i < 3; i++) {
            ushort4 u = *(const ushort4*)(kv + (m * 13 + l) * 768 + i * 256 + lane * 4);
            float xv[4] = {bf2f(u.x), bf2f(u.y), bf2f(u.z), bf2f(u.w)};
#pragma unroll
            for (int h = 0; h < 4; h++)
#pragma unroll
                for (int e = 0; e < 4; e++) acc[h][i][e] += al[h] * xv[e];
        }
    }
#pragma unroll
    for (int h = 0; h < 4; h++) {
        float ch = latc[wave][h];
#pragma unroll
        for (int i = 0; i < 3; i++) {
            ushort4 o;
            o.x = f2bf(g4v[i][0] * (acc[h][i][0] - ch) + b4[i][0]);
            o.y = f2bf(g4v[i][1] * (acc[h][i][1] - ch) + b4[i][1]);
            o.z = f2bf(g4v[i][2] * (acc[h][i][2] - ch) + b4[i][2]);
            o.w = f2bf(g4v[i][3] * (acc[h][i][3] - ch) + b4[i][3]);
            *(ushort4*)(oh + m * 3072 + h * 768 + i * 256 + lane * 4) = o;
        }
    }
}

// ---------------------------------------------------------------------------
extern "C" void kernel_launch(void* const* d_in, const int* in_sizes, int n_in,
                              void* d_out, int out_size, void* d_ws, size_t ws_size,
                              hipStream_t stream) {
    const float* base  = (const float*)d_in[0];
    const float* reps  = (const float*)d_in[1];
    const float* aw    = (const float*)d_in[2];
    const float* ab    = (const float*)d_in[3];
    const float* qg    = (const float*)d_in[4];
    const float* qbeta = (const float*)d_in[5];
    const float* kvg   = (const float*)d_in[6];
    const float* kvb   = (const float*)d_in[7];
    const float* qw    = (const float*)d_in[8];
    const float* qbias = (const float*)d_in[9];
    const float* kw    = (const float*)d_in[10];
    const float* kbias = (const float*)d_in[11];
    const float* ow    = (const float*)d_in[12];
    const float* obias = (const float*)d_in[13];
    float* out = (float*)d_out;

    float2* stats = (float2*)d_ws;                              // [MROWS]
    float* kwp = (float*)(stats + MROWS);                       // [32][768]
    float* skv = kwp + 32 * 768;                                // [32]
    float* ckv = skv + 32;                                      // [32]
    unsigned short* aligned = (unsigned short*)(ckv + 32);      // [MROWS][768]
    unsigned short* UNION = aligned + (size_t)MROWS * 768;      // awb -> Qn -> oh
    unsigned short* kbuf = UNION + (size_t)MTOK * 3072;         // [MROWS][32]
    unsigned short* qbuf = kbuf + (size_t)MROWS * 32;           // [MTOK][32]
    unsigned short* owb  = qbuf + (size_t)MTOK * 32;            // [768][3072]

    unsigned short* awb = UNION;

    // 0. weight conversions + LN folding precompute
    {
        long n = (long)NL * 768 * 768;
        conv_f32_bf16<<<(int)(n / 8 / 256), 256, 0, stream>>>(aw, awb, n);
        long n2 = (long)768 * 3072;
        conv_f32_bf16<<<(int)(n2 / 8 / 256), 256, 0, stream>>>(ow, owb, n2);
        wtrans<<<32, 256, 0, stream>>>(kw, kvg, kvb, kbias, kwp, skv, ckv);
    }

    // 1. aligner GEMM (XCD-grouped; BK=64, issue-early/write-late)
    gemm_f32a<<<4992, 256, 0, stream>>>(
        reps, awb, ab, aligned,
        (long)MTOK * 768, (long)768 * 768, 768,
        768L, (long)NL * 768);

    // 2. k projection + fused row stats
    proj32k_stats<<<MROWS / 128, 256, 0, stream>>>(
        aligned, kwp, skv, ckv, kbuf, stats);

    // 3. q side: LN(base) -> Qn, then proj32 (awb dead, reuse UNION)
    unsigned short* Qn = UNION;
    ln_rows_f32<<<MTOK / 4, 256, 0, stream>>>(base, Qn, qg, qbeta);
    proj32<<<MTOK / 128, 256, 0, stream>>>(Qn, qw, qbias, qbuf);

    // 4. attention on raw aligned (Qn dead, reuse UNION for oh)
    unsigned short* oh = UNION;
    attn2<<<MTOK / 4, 256, 0, stream>>>(qbuf, kbuf, aligned, stats, kvg, kvb, oh);

    // 5. out = out_heads @ out_w^T + out_b
    gemm_bf16_nt<<<384, 256, 0, stream>>>(oh, owb, obias, out, 3072, 768L);
}

// Round 10
// 462.155 us; speedup vs baseline: 1.3879x; 1.3879x over previous
//
#include <hip/hip_runtime.h>
#include <stdint.h>

#define NB 8
#define NT 1024
#define ND 768
#define NV 768
#define NL 13
#define MTOK (NB*NT)          // 8192
#define MROWS (MTOK*NL)       // 106496

typedef __attribute__((ext_vector_type(8))) short short8;
typedef __attribute__((ext_vector_type(4))) float f32x4;

__device__ __forceinline__ unsigned short f2bf(float f) {
    union { float f; unsigned u; } v; v.f = f;
    unsigned r = v.u + 0x7FFFu + ((v.u >> 16) & 1u);
    return (unsigned short)(r >> 16);
}
__device__ __forceinline__ float bf2f(unsigned short u) {
    union { unsigned u; float f; } v; v.u = ((unsigned)u) << 16;
    return v.f;
}
__device__ __forceinline__ unsigned cvtpk(float lo, float hi) {
    unsigned r;
    asm("v_cvt_pk_bf16_f32 %0, %1, %2" : "=v"(r) : "v"(lo), "v"(hi));
    return r;
}
__device__ __forceinline__ void gload16(const void* g, void* l) {
    __builtin_amdgcn_global_load_lds(
        (const __attribute__((address_space(1))) unsigned int*)g,
        (__attribute__((address_space(3))) unsigned int*)l, 16, 0, 0);
}

#define BARRAW { __builtin_amdgcn_s_barrier(); __builtin_amdgcn_sched_barrier(0); }

// ---------------------------------------------------------------------------
// fp32 -> bf16 bulk convert (weights only)
// ---------------------------------------------------------------------------
__global__ __launch_bounds__(256) void conv_f32_bf16(
    const float* __restrict__ s, unsigned short* __restrict__ d, long n)
{
    long i = ((long)blockIdx.x * 256 + threadIdx.x) * 8;
    long st = (long)gridDim.x * 2048;
    for (; i < n; i += st) {
        float4 a = *(const float4*)(s + i);
        float4 b = *(const float4*)(s + i + 4);
        ushort4 u0, u1;
        u0.x = f2bf(a.x); u0.y = f2bf(a.y); u0.z = f2bf(a.z); u0.w = f2bf(a.w);
        u1.x = f2bf(b.x); u1.y = f2bf(b.y); u1.z = f2bf(b.z); u1.w = f2bf(b.w);
        *(ushort4*)(d + i)     = u0;
        *(ushort4*)(d + i + 4) = u1;
    }
}

// ---------------------------------------------------------------------------
// GEMM1: C(bf16) = A(fp32) * B(bf16)^T + bias.  K=768, BK=32, 24 K-tiles.
// 256x256 tile, 8 waves (2M x 4N), per-wave 128x64.  4 phases per K-tile:
//  P0: LOADA(next)->regs | bv ds_reads | 8 MFMA | raw barrier
//  P1: STAGEB(next) gload_lds         | 8 MFMA | raw barrier
//  P2: WRITEA(next) cvt+ds_write      | 8 MFMA | raw barrier
//  P3: 8 MFMA | vmcnt(0)+lgkm(0) | barrier   (single counted drain per tile)
// setprio(1) around each MFMA cluster (T5).  XCD-grouped grid 1248 =
// 8 XCD x 52 (layer,m)-groups x 3 n-blocks.
// ---------------------------------------------------------------------------
__global__ __launch_bounds__(512, 2) void gemm_f32a(
    const float* __restrict__ A, const unsigned short* __restrict__ B,
    const float* __restrict__ biasBase, unsigned short* __restrict__ C,
    long aLS, long bLS, int biasLS, long cLayerOff, long cRowStride)
{
    __shared__ __align__(16) unsigned short lsA[2][256 * 40];  // padded bf16
    __shared__ __align__(16) unsigned short lsB[2][256 * 32];  // linear bf16

    const int bid = blockIdx.x;
    const int xcd = bid & 7, slot = bid >> 3;        // 156 slots per XCD
    const int grp = xcd * 52 + slot / 3;             // 0..415
    const int nx  = slot % 3;
    const int l   = grp >> 5;                        // layer 0..12
    const long m0 = (long)(grp & 31) * 256;
    const long n0 = (long)nx * 256;

    const int t = threadIdx.x, lane = t & 63, wave = t >> 6;

    const float* Ab = A + (size_t)l * aLS;
    const unsigned short* Bb = B + (size_t)l * bLS;
    const float* bias = biasBase + (size_t)l * biasLS;

    // A reg staging: thread covers row t>>1, k-half t&1 (16 floats)
    const int aRow  = t >> 1;            // 0..255
    const int aHalf = t & 1;
    const float* aSrc = Ab + (m0 + aRow) * (size_t)768 + aHalf * 16;

    // B staging: linear dest, XOR source chunk (verified pair from R5/R6)
    const int brow0 = wave * 16 + (lane >> 2);       // 0..127 (+128 via i)
    const int bchk  = (lane & 3) ^ ((lane >> 3) & 3);
    const int dB0   = wave * 1024 + lane * 16;       // bytes within 8KB slab
    const unsigned short* bSp0 = Bb + (n0 + brow0) * (size_t)768 + bchk * 8;
    const unsigned short* bSp1 = Bb + (n0 + 128 + brow0) * (size_t)768 + bchk * 8;

    const int wm = (wave >> 2) * 128;    // 2 M-waves
    const int wn = (wave & 3) * 64;      // 4 N-waves
    const int lr = lane & 15;
    const int g4 = lane >> 4;
    const int kg = g4 * 8;
    const int swzB = ((lr >> 1) & 3) * 8;

    f32x4 acc[8][4];
#pragma unroll
    for (int i = 0; i < 8; i++)
#pragma unroll
        for (int j = 0; j < 4; j++) acc[i][j] = (f32x4){0.f, 0.f, 0.f, 0.f};

    f32x4 areg[4];

    auto LOADA = [&](int k0) {
#pragma unroll
        for (int i = 0; i < 4; i++)
            areg[i] = *(const f32x4*)(aSrc + k0 + i * 4);
    };
    auto WRITEA = [&](int buf) {
        unsigned short* la = lsA[buf];
#pragma unroll
        for (int i = 0; i < 4; i++) {
            uint2 w;
            w.x = cvtpk(areg[i][0], areg[i][1]);
            w.y = cvtpk(areg[i][2], areg[i][3]);
            *(uint2*)&la[aRow * 40 + aHalf * 16 + i * 4] = w;
        }
    };
    auto STAGEB = [&](int buf, int k0) {
        char* lb = (char*)lsB[buf];
        gload16(bSp0 + k0, lb + dB0);
        gload16(bSp1 + k0, lb + 8192 + dB0);
    };

#define MFMA_PAIR(pa_, bv_, p) { \
    short8 a0_ = *(const short8*)&(pa_)[(wm + (2*(p)) * 16 + lr) * 40 + kg]; \
    short8 a1_ = *(const short8*)&(pa_)[(wm + (2*(p)+1) * 16 + lr) * 40 + kg]; \
    __builtin_amdgcn_s_setprio(1); \
    _Pragma("unroll") \
    for (int ni_ = 0; ni_ < 4; ni_++) \
        acc[2*(p)][ni_] = __builtin_amdgcn_mfma_f32_16x16x32_bf16( \
            a0_, (bv_)[ni_], acc[2*(p)][ni_], 0, 0, 0); \
    _Pragma("unroll") \
    for (int ni_ = 0; ni_ < 4; ni_++) \
        acc[2*(p)+1][ni_] = __builtin_amdgcn_mfma_f32_16x16x32_bf16( \
            a1_, (bv_)[ni_], acc[2*(p)+1][ni_], 0, 0, 0); \
    __builtin_amdgcn_s_setprio(0); }

    // Prologue: tile0 -> buf0 (A via regs, B via gload_lds), full drain.
    LOADA(0);
    STAGEB(0, 0);
    WRITEA(0);
    asm volatile("s_waitcnt vmcnt(0) lgkmcnt(0)" ::: "memory");
    BARRAW;

    for (int ks = 0; ks < 24; ks++) {
        const int cur = ks & 1;
        const unsigned short* pa = lsA[cur];
        const unsigned short* pb = lsB[cur];
        const bool pf = (ks < 23);
        // P0
        if (pf) LOADA((ks + 1) * 32);
        short8 bv[4];
#pragma unroll
        for (int ni = 0; ni < 4; ni++)
            bv[ni] = *(const short8*)&pb[(wn + ni * 16 + lr) * 32 + (kg ^ swzB)];
        MFMA_PAIR(pa, bv, 0);
        BARRAW;
        // P1
        if (pf) STAGEB(cur ^ 1, (ks + 1) * 32);
        MFMA_PAIR(pa, bv, 1);
        BARRAW;
        // P2
        if (pf) WRITEA(cur ^ 1);
        MFMA_PAIR(pa, bv, 2);
        BARRAW;
        // P3
        MFMA_PAIR(pa, bv, 3);
        asm volatile("s_waitcnt vmcnt(0) lgkmcnt(0)" ::: "memory");
        BARRAW;
    }
#undef MFMA_PAIR

#pragma unroll
    for (int ni = 0; ni < 4; ni++) {
        long col = n0 + wn + ni * 16 + lr;
        float bvs = bias[col];
#pragma unroll
        for (int mi = 0; mi < 8; mi++) {
#pragma unroll
            for (int r = 0; r < 4; r++) {
                long grow = m0 + wm + mi * 16 + g4 * 4 + r;
                size_t coff = (size_t)grow * cRowStride + (size_t)l * cLayerOff + col;
                C[coff] = f2bf(acc[mi][ni][r] + bvs);
            }
        }
    }
}

// ---------------------------------------------------------------------------
// GEMM2: C(f32) = A(bf16) * B(bf16)^T + bias.  64x128 tile, BK=32, gload
// staging + XOR swizzle (R6-verified scheme), grid 768 = 8 x 16 x 6.
// ---------------------------------------------------------------------------
__global__ __launch_bounds__(256) void gemm_bf16_nt(
    const unsigned short* __restrict__ A, const unsigned short* __restrict__ B,
    const float* __restrict__ bias, float* __restrict__ C,
    int K, long cRowStride)
{
    __shared__ __align__(16) unsigned short lsA[2][64 * 32];
    __shared__ __align__(16) unsigned short lsB[2][128 * 32];

    const int bid = blockIdx.x;
    const int xcd = bid & 7, slot = bid >> 3;        // 96 slots per XCD
    const int grp = xcd * 16 + slot / 6;             // 0..127 m-blocks
    const int nx  = slot % 6;
    const long m0 = (long)grp * 64;
    const long n0 = (long)nx * 128;

    const int t = threadIdx.x, lane = t & 63, wave = t >> 6;

    const int srow = wave * 16 + (lane >> 2);        // 0..63
    const int schk = (lane & 3) ^ ((lane >> 3) & 3);
    const int dS   = wave * 1024 + lane * 16;

    const int wm = (wave >> 1) * 32;
    const int wn = (wave & 1) * 64;
    const int lr = lane & 15;
    const int g4 = lane >> 4;
    const int kg = g4 * 8;
    const int swz = ((lr >> 1) & 3) * 8;

    const unsigned short* aSp  = A + (m0 + srow) * (size_t)K + schk * 8;
    const unsigned short* bSp0 = B + (n0 + srow) * (size_t)K + schk * 8;
    const unsigned short* bSp1 = B + (n0 + 64 + srow) * (size_t)K + schk * 8;

    f32x4 acc[2][4];
#pragma unroll
    for (int i = 0; i < 2; i++)
#pragma unroll
        for (int j = 0; j < 4; j++) acc[i][j] = (f32x4){0.f, 0.f, 0.f, 0.f};

    auto STAGE = [&](int buf, int k0) {
        char* la = (char*)lsA[buf];
        char* lb = (char*)lsB[buf];
        gload16(aSp + k0, la + dS);
        gload16(bSp0 + k0, lb + dS);
        gload16(bSp1 + k0, lb + 4096 + dS);
    };
    auto COMP = [&](int buf) {
        short8 af[2], bv[4];
        const unsigned short* pa = lsA[buf];
        const unsigned short* pb = lsB[buf];
#pragma unroll
        for (int mi = 0; mi < 2; mi++)
            af[mi] = *(const short8*)&pa[(wm + mi * 16 + lr) * 32 + (kg ^ swz)];
#pragma unroll
        for (int ni = 0; ni < 4; ni++)
            bv[ni] = *(const short8*)&pb[(wn + ni * 16 + lr) * 32 + (kg ^ swz)];
#pragma unroll
        for (int mi = 0; mi < 2; mi++)
#pragma unroll
            for (int ni = 0; ni < 4; ni++)
                acc[mi][ni] = __builtin_amdgcn_mfma_f32_16x16x32_bf16(
                    af[mi], bv[ni], acc[mi][ni], 0, 0, 0);
    };

    STAGE(0, 0);
    __syncthreads();
    int cur = 0;
    const int nst = K >> 5;
    for (int ks = 1; ks < nst; ks++) {
        STAGE(cur ^ 1, ks * 32);
        COMP(cur);
        __syncthreads();
        cur ^= 1;
    }
    COMP(cur);

#pragma unroll
    for (int ni = 0; ni < 4; ni++) {
        long col = n0 + wn + ni * 16 + lr;
        float bvs = bias[col];
#pragma unroll
        for (int mi = 0; mi < 2; mi++) {
#pragma unroll
            for (int r = 0; r < 4; r++) {
                long grow = m0 + wm + mi * 16 + g4 * 4 + r;
                C[(size_t)grow * cRowStride + col] = acc[mi][ni][r] + bvs;
            }
        }
    }
}

// ---------------------------------------------------------------------------
// Fold kvln gamma into k_w; compute s_k = sum(kw*g), c_k = kw.b + k_bias.
// ---------------------------------------------------------------------------
__global__ __launch_bounds__(256) void wtrans(
    const float* __restrict__ kw, const float* __restrict__ kvg,
    const float* __restrict__ kvb, const float* __restrict__ kbias,
    float* __restrict__ kwp, float* __restrict__ skv, float* __restrict__ ckv)
{
    __shared__ float red[8];
    const int q = blockIdx.x, t = threadIdx.x;
    const int lane = t & 63, wave = t >> 6;
    float s = 0.f, c = 0.f;
    for (int v = t; v < 768; v += 256) {
        float w = kw[q * 768 + v];
        float wp = w * kvg[v];
        kwp[q * 768 + v] = wp;
        s += wp;
        c += w * kvb[v];
    }
#pragma unroll
    for (int off = 1; off < 64; off <<= 1) {
        s += __shfl_xor(s, off);
        c += __shfl_xor(c, off);
    }
    if (lane == 0) { red[wave] = s; red[4 + wave] = c; }
    __syncthreads();
    if (t == 0) {
        skv[q] = red[0] + red[1] + red[2] + red[3];
        ckv[q] = red[4] + red[5] + red[6] + red[7] + kbias[q];
    }
}

// ---------------------------------------------------------------------------
// LayerNorm rows of 768 (fp32 src) -> bf16.  Q side only.
// ---------------------------------------------------------------------------
__global__ __launch_bounds__(256) void ln_rows_f32(
    const float* __restrict__ src, unsigned short* __restrict__ dst,
    const float* __restrict__ gam, const float* __restrict__ bet)
{
    const int lane = threadIdx.x & 63;
    const int wave = threadIdx.x >> 6;
    const size_t row = (size_t)blockIdx.x * 4 + wave;

    float x[3][4];
    float s = 0.f, sq = 0.f;
#pragma unroll
    for (int i = 0; i < 3; i++) {
        int v = i * 256 + lane * 4;
        float4 f = *(const float4*)(src + row * 768 + v);
        x[i][0] = f.x; x[i][1] = f.y; x[i][2] = f.z; x[i][3] = f.w;
#pragma unroll
        for (int e = 0; e < 4; e++) { s += x[i][e]; sq += x[i][e] * x[i][e]; }
    }
#pragma unroll
    for (int off = 1; off < 64; off <<= 1) {
        s  += __shfl_xor(s, off);
        sq += __shfl_xor(sq, off);
    }
    float mean = s * (1.f / 768.f);
    float var  = sq * (1.f / 768.f) - mean * mean;
    float rs   = rsqrtf(var + 1e-5f);
#pragma unroll
    for (int i = 0; i < 3; i++) {
        int v = i * 256 + lane * 4;
        float4 gg = *(const float4*)(gam + v);
        float4 bb = *(const float4*)(bet + v);
        ushort4 o;
        o.x = f2bf((x[i][0] - mean) * rs * gg.x + bb.x);
        o.y = f2bf((x[i][1] - mean) * rs * gg.y + bb.y);
        o.z = f2bf((x[i][2] - mean) * rs * gg.z + bb.z);
        o.w = f2bf((x[i][3] - mean) * rs * gg.w + bb.w);
        *(ushort4*)(dst + row * 768 + v) = o;
    }
}

// ---------------------------------------------------------------------------
// proj32: out[M][32] = A[M][768](bf16) @ W[32][768](f32)^T + bias (plain).
// ---------------------------------------------------------------------------
__global__ __launch_bounds__(256) void proj32(
    const unsigned short* __restrict__ A, const float* __restrict__ W,
    const float* __restrict__ bias, unsigned short* __restrict__ out)
{
    __shared__ __align__(16) unsigned short lsW[32 * 776];
    __shared__ __align__(16) unsigned short lsA[128 * 40];
    const int t = threadIdx.x;

#pragma unroll
    for (int i = 0; i < 24; i++) {
        int fi = t + i * 256;
        int row = fi / 192;
        int c4  = fi % 192;
        float4 f = *(const float4*)(W + row * 768 + c4 * 4);
        ushort4 u;
        u.x = f2bf(f.x); u.y = f2bf(f.y); u.z = f2bf(f.z); u.w = f2bf(f.w);
        *(ushort4*)&lsW[row * 776 + c4 * 4] = u;
    }

    const size_t m0 = (size_t)blockIdx.x * 128;
    const int lane = t & 63, wave = t >> 6;
    const int wm = wave * 32;
    const int lr = lane & 15, kg = (lane >> 4) * 8;
    const int row_s = t >> 3, c4s = t & 7;

    f32x4 acc[2][2];
#pragma unroll
    for (int i = 0; i < 2; i++)
#pragma unroll
        for (int j = 0; j < 2; j++) acc[i][j] = (f32x4){0.f, 0.f, 0.f, 0.f};

    __syncthreads();

    for (int k0 = 0; k0 < 768; k0 += 32) {
#pragma unroll
        for (int i = 0; i < 4; i++) {
            int row = row_s + 32 * i;
            ushort4 v = *(const ushort4*)(A + (m0 + row) * 768 + k0 + c4s * 4);
            *(ushort4*)&lsA[row * 40 + c4s * 4] = v;
        }
        __syncthreads();
        short8 af[2], bw[2];
#pragma unroll
        for (int mi = 0; mi < 2; mi++)
            af[mi] = *(const short8*)&lsA[(wm + mi * 16 + lr) * 40 + kg];
#pragma unroll
        for (int ni = 0; ni < 2; ni++)
            bw[ni] = *(const short8*)&lsW[(ni * 16 + lr) * 776 + k0 + kg];
#pragma unroll
        for (int mi = 0; mi < 2; mi++)
#pragma unroll
            for (int ni = 0; ni < 2; ni++)
                acc[mi][ni] = __builtin_amdgcn_mfma_f32_16x16x32_bf16(
                    af[mi], bw[ni], acc[mi][ni], 0, 0, 0);
        __syncthreads();
    }

#pragma unroll
    for (int ni = 0; ni < 2; ni++) {
        int col = ni * 16 + lr;
        float bv = bias[col];
#pragma unroll
        for (int mi = 0; mi < 2; mi++) {
#pragma unroll
            for (int r = 0; r < 4; r++) {
                size_t grow = m0 + wm + mi * 16 + (lane >> 4) * 4 + r;
                out[grow * 32 + col] = f2bf(acc[mi][ni][r] + bv);
            }
        }
    }
}

// ---------------------------------------------------------------------------
// proj32k_stats: k = rs*(dot(x_raw, kwp) - mean*s_k) + c_k, with row stats
// computed in the K-loop.
// ---------------------------------------------------------------------------
__global__ __launch_bounds__(256) void proj32k_stats(
    const unsigned short* __restrict__ A, const float* __restrict__ W,
    const float* __restrict__ skv, const float* __restrict__ ckv,
    unsigned short* __restrict__ out, float2* __restrict__ st)
{
    __shared__ __align__(16) unsigned short lsW[32 * 776];
    __shared__ __align__(16) unsigned short lsA[128 * 40];
    __shared__ float2 lstat[128];
    const int t = threadIdx.x;

#pragma unroll
    for (int i = 0; i < 24; i++) {
        int fi = t + i * 256;
        int row = fi / 192;
        int c4  = fi % 192;
        float4 f = *(const float4*)(W + row * 768 + c4 * 4);
        ushort4 u;
        u.x = f2bf(f.x); u.y = f2bf(f.y); u.z = f2bf(f.z); u.w = f2bf(f.w);
        *(ushort4*)&lsW[row * 776 + c4 * 4] = u;
    }

    const size_t m0 = (size_t)blockIdx.x * 128;
    const int lane = t & 63, wave = t >> 6;
    const int wm = wave * 32;
    const int lr = lane & 15, kg = (lane >> 4) * 8;
    const int row_s = t >> 3, c4s = t & 7;

    f32x4 acc[2][2];
#pragma unroll
    for (int i = 0; i < 2; i++)
#pragma unroll
        for (int j = 0; j < 2; j++) acc[i][j] = (f32x4){0.f, 0.f, 0.f, 0.f};

    float s_[4] = {0.f, 0.f, 0.f, 0.f}, sq_[4] = {0.f, 0.f, 0.f, 0.f};

    __syncthreads();

    for (int k0 = 0; k0 < 768; k0 += 32) {
#pragma unroll
        for (int i = 0; i < 4; i++) {
            int row = row_s + 32 * i;
            ushort4 v = *(const ushort4*)(A + (m0 + row) * 768 + k0 + c4s * 4);
            *(ushort4*)&lsA[row * 40 + c4s * 4] = v;
            float x0 = bf2f(v.x), x1 = bf2f(v.y), x2 = bf2f(v.z), x3 = bf2f(v.w);
            s_[i]  += x0 + x1 + x2 + x3;
            sq_[i] += x0 * x0 + x1 * x1 + x2 * x2 + x3 * x3;
        }
        __syncthreads();
        short8 af[2], bw[2];
#pragma unroll
        for (int mi = 0; mi < 2; mi++)
            af[mi] = *(const short8*)&lsA[(wm + mi * 16 + lr) * 40 + kg];
#pragma unroll
        for (int ni = 0; ni < 2; ni++)
            bw[ni] = *(const short8*)&lsW[(ni * 16 + lr) * 776 + k0 + kg];
#pragma unroll
        for (int mi = 0; mi < 2; mi++)
#pragma unroll
            for (int ni = 0; ni < 2; ni++)
                acc[mi][ni] = __builtin_amdgcn_mfma_f32_16x16x32_bf16(
                    af[mi], bw[ni], acc[mi][ni], 0, 0, 0);
        __syncthreads();
    }

#pragma unroll
    for (int i = 0; i < 4; i++) {
#pragma unroll
        for (int off = 1; off < 8; off <<= 1) {
            s_[i]  += __shfl_xor(s_[i], off);
            sq_[i] += __shfl_xor(sq_[i], off);
        }
    }
    if (c4s == 0) {
#pragma unroll
        for (int i = 0; i < 4; i++) {
            int row = row_s + 32 * i;
            float mean = s_[i] * (1.f / 768.f);
            float var  = sq_[i] * (1.f / 768.f) - mean * mean;
            float2 sv = make_float2(mean, rsqrtf(var + 1e-5f));
            lstat[row] = sv;
            st[m0 + row] = sv;
        }
    }
    __syncthreads();

#pragma unroll
    for (int ni = 0; ni < 2; ni++) {
        int col = ni * 16 + lr;
        float sk = skv[col], ck = ckv[col];
#pragma unroll
        for (int mi = 0; mi < 2; mi++) {
#pragma unroll
            for (int r = 0; r < 4; r++) {
                int lrow = wm + mi * 16 + (lane >> 4) * 4 + r;
                float2 s2 = lstat[lrow];
                out[(m0 + lrow) * 32 + col] =
                    f2bf(s2.y * (acc[mi][ni][r] - s2.x * sk) + ck);
            }
        }
    }
}

// ---------------------------------------------------------------------------
// Attention on RAW aligned values with LN folded in.  One wave per token.
// ---------------------------------------------------------------------------
__global__ __launch_bounds__(256) void attn2(
    const unsigned short* __restrict__ qb, const unsigned short* __restrict__ kb,
    const unsigned short* __restrict__ kv, const float2* __restrict__ st,
    const float* __restrict__ gv, const float* __restrict__ bvv,
    unsigned short* __restrict__ oh)
{
    __shared__ float lat[4][4][13];
    __shared__ float latc[4][4];
    const int t = threadIdx.x, lane = t & 63, wave = t >> 6;
    const size_t m = (size_t)blockIdx.x * 4 + wave;

    if (lane < 32) {
        int j = lane;
        float qv = bf2f(qb[m * 32 + j]);
        float p[13];
#pragma unroll
        for (int l = 0; l < 13; l++)
            p[l] = qv * bf2f(kb[(m * 13 + l) * 32 + j]);
#pragma unroll
        for (int off = 1; off < 8; off <<= 1)
#pragma unroll
            for (int l = 0; l < 13; l++) p[l] += __shfl_xor(p[l], off);

        const float sc = 0.17677669529663687f; // 1 / (sqrt(8) * 2)
        float mx = -1e30f;
#pragma unroll
        for (int l = 0; l < 13; l++) { p[l] *= sc; mx = fmaxf(mx, p[l]); }
        float se = 0.f;
#pragma unroll
        for (int l = 0; l < 13; l++) { p[l] = __expf(p[l] - mx); se += p[l]; }
        float inv = 1.f / se;
        if ((j & 7) == 0) {
            int h = j >> 3;
            float corr = 0.f;
#pragma unroll
            for (int l = 0; l < 13; l++) {
                float2 s_ = st[m * 13 + l];
                float wl = p[l] * inv * s_.y;
                lat[wave][h][l] = wl;
                corr += wl * s_.x;
            }
            latc[wave][h] = corr;
        }
    }
    __syncthreads();

    f32x4 g4v[3], b4[3];
#pragma unroll
    for (int i = 0; i < 3; i++) {
        g4v[i] = *(const f32x4*)(gv + i * 256 + lane * 4);
        b4[i] = *(const f32x4*)(bvv + i * 256 + lane * 4);
    }

    float acc[4][3][4];
#pragma unroll
    for (int h = 0; h < 4; h++)
#pragma unroll
        for (int i = 0; i < 3; i++)
#pragma unroll
            for (int e = 0; e < 4; e++) acc[h][i][e] = 0.f;

    for (int l = 0; l < 13; l++) {
        float al[4];
#pragma unroll
        for (int h = 0; h < 4; h++) al[h] = lat[wave][h][l];
#pragma unroll
        for (int i = 0; i < 3; i++) {
            ushort4 u = *(const ushort4*)(kv + (m * 13 + l) * 768 + i * 256 + lane * 4);
            float xv[4] = {bf2f(u.x), bf2f(u.y), bf2f(u.z), bf2f(u.w)};
#pragma unroll
            for (int h = 0; h < 4; h++)
#pragma unroll
                for (int e = 0; e < 4; e++) acc[h][i][e] += al[h] * xv[e];
        }
    }
#pragma unroll
    for (int h = 0; h < 4; h++) {
        float ch = latc[wave][h];
#pragma unroll
        for (int i = 0; i < 3; i++) {
            ushort4 o;
            o.x = f2bf(g4v[i][0] * (acc[h][i][0] - ch) + b4[i][0]);
            o.y = f2bf(g4v[i][1] * (acc[h][i][1] - ch) + b4[i][1]);
            o.z = f2bf(g4v[i][2] * (acc[h][i][2] - ch) + b4[i][2]);
            o.w = f2bf(g4v[i][3] * (acc[h][i][3] - ch) + b4[i][3]);
            *(ushort4*)(oh + m * 3072 + h * 768 + i * 256 + lane * 4) = o;
        }
    }
}

// ---------------------------------------------------------------------------
extern "C" void kernel_launch(void* const* d_in, const int* in_sizes, int n_in,
                              void* d_out, int out_size, void* d_ws, size_t ws_size,
                              hipStream_t stream) {
    const float* base  = (const float*)d_in[0];
    const float* reps  = (const float*)d_in[1];
    const float* aw    = (const float*)d_in[2];
    const float* ab    = (const float*)d_in[3];
    const float* qg    = (const float*)d_in[4];
    const float* qbeta = (const float*)d_in[5];
    const float* kvg   = (const float*)d_in[6];
    const float* kvb   = (const float*)d_in[7];
    const float* qw    = (const float*)d_in[8];
    const float* qbias = (const float*)d_in[9];
    const float* kw    = (const float*)d_in[10];
    const float* kbias = (const float*)d_in[11];
    const float* ow    = (const float*)d_in[12];
    const float* obias = (const float*)d_in[13];
    float* out = (float*)d_out;

    float2* stats = (float2*)d_ws;                              // [MROWS]
    float* kwp = (float*)(stats + MROWS);                       // [32][768]
    float* skv = kwp + 32 * 768;                                // [32]
    float* ckv = skv + 32;                                      // [32]
    unsigned short* aligned = (unsigned short*)(ckv + 32);      // [MROWS][768]
    unsigned short* UNION = aligned + (size_t)MROWS * 768;      // awb -> Qn -> oh
    unsigned short* kbuf = UNION + (size_t)MTOK * 3072;         // [MROWS][32]
    unsigned short* qbuf = kbuf + (size_t)MROWS * 32;           // [MTOK][32]
    unsigned short* owb  = qbuf + (size_t)MTOK * 32;            // [768][3072]

    unsigned short* awb = UNION;

    // 0. weight conversions + LN folding precompute
    {
        long n = (long)NL * 768 * 768;
        conv_f32_bf16<<<(int)(n / 8 / 256), 256, 0, stream>>>(aw, awb, n);
        long n2 = (long)768 * 3072;
        conv_f32_bf16<<<(int)(n2 / 8 / 256), 256, 0, stream>>>(ow, owb, n2);
        wtrans<<<32, 256, 0, stream>>>(kw, kvg, kvb, kbias, kwp, skv, ckv);
    }

    // 1. aligner GEMM: 256^2 tile, 8 waves, 4-phase schedule, 1248 blocks
    gemm_f32a<<<1248, 512, 0, stream>>>(
        reps, awb, ab, aligned,
        (long)MTOK * 768, (long)768 * 768, 768,
        768L, (long)NL * 768);

    // 2. k projection + fused row stats
    proj32k_stats<<<MROWS / 128, 256, 0, stream>>>(
        aligned, kwp, skv, ckv, kbuf, stats);

    // 3. q side: LN(base) -> Qn, then proj32 (awb dead, reuse UNION)
    unsigned short* Qn = UNION;
    ln_rows_f32<<<MTOK / 4, 256, 0, stream>>>(base, Qn, qg, qbeta);
    proj32<<<MTOK / 128, 256, 0, stream>>>(Qn, qw, qbias, qbuf);

    // 4. attention on raw aligned (Qn dead, reuse UNION for oh)
    unsigned short* oh = UNION;
    attn2<<<MTOK / 4, 256, 0, stream>>>(qbuf, kbuf, aligned, stats, kvg, kvb, oh);

    // 5. out = out_heads @ out_w^T + out_b (64x128 tiles, 768 blocks)
    gemm_bf16_nt<<<768, 256, 0, stream>>>(oh, owb, obias, out, 3072, 768L);
}

// Round 11
// 438.178 us; speedup vs baseline: 1.4638x; 1.0547x over previous
//
#include <hip/hip_runtime.h>
#include <stdint.h>

#define NB 8
#define NT 1024
#define ND 768
#define NV 768
#define NL 13
#define MTOK (NB*NT)          // 8192
#define MROWS (MTOK*NL)       // 106496

typedef __attribute__((ext_vector_type(8))) short short8;
typedef __attribute__((ext_vector_type(4))) float f32x4;

__device__ __forceinline__ unsigned short f2bf(float f) {
    union { float f; unsigned u; } v; v.f = f;
    unsigned r = v.u + 0x7FFFu + ((v.u >> 16) & 1u);
    return (unsigned short)(r >> 16);
}
__device__ __forceinline__ float bf2f(unsigned short u) {
    union { unsigned u; float f; } v; v.u = ((unsigned)u) << 16;
    return v.f;
}
__device__ __forceinline__ unsigned cvtpk(float lo, float hi) {
    unsigned r;
    asm("v_cvt_pk_bf16_f32 %0, %1, %2" : "=v"(r) : "v"(lo), "v"(hi));
    return r;
}
__device__ __forceinline__ void gload16(const void* g, void* l) {
    __builtin_amdgcn_global_load_lds(
        (const __attribute__((address_space(1))) unsigned int*)g,
        (__attribute__((address_space(3))) unsigned int*)l, 16, 0, 0);
}

#define PHB { __builtin_amdgcn_s_barrier(); __builtin_amdgcn_sched_barrier(0); }

// ---------------------------------------------------------------------------
// fp32 -> bf16 bulk convert (weights only)
// ---------------------------------------------------------------------------
__global__ __launch_bounds__(256) void conv_f32_bf16(
    const float* __restrict__ s, unsigned short* __restrict__ d, long n)
{
    long i = ((long)blockIdx.x * 256 + threadIdx.x) * 8;
    long st = (long)gridDim.x * 2048;
    for (; i < n; i += st) {
        float4 a = *(const float4*)(s + i);
        float4 b = *(const float4*)(s + i + 4);
        ushort4 u0, u1;
        u0.x = f2bf(a.x); u0.y = f2bf(a.y); u0.z = f2bf(a.z); u0.w = f2bf(a.w);
        u1.x = f2bf(b.x); u1.y = f2bf(b.y); u1.z = f2bf(b.z); u1.w = f2bf(b.w);
        *(ushort4*)(d + i)     = u0;
        *(ushort4*)(d + i + 4) = u1;
    }
}

// ---------------------------------------------------------------------------
// GEMM1: C(bf16) = A(fp32) * B(bf16)^T + bias.  K=768, BK=32, 24 K-tiles.
// 256x256 tile, 8 waves (2M x 4N), per-wave 128x64.
// 3 LDS buffers (tiles t, t+1 resident; t+2 staged) x (A,B) pad-40 rows.
// All staging via registers (A: fp32->cvt_pk; B: bf16 copy) -> ds_write,
// so BOTH operand layouts are padded (conflict-free 2-way reads) and all
// vmcnt waits are compiler-inserted register dependences.
// Per tile, 4 phases: P0{LOADA(t+2) | bv reads | 8 MFMA}, P1{LOADB(t+2) |
// 8 MFMA}, P2{WRITEA/B(t+1) | 8 MFMA}, P3{8 MFMA | lgkmcnt(0)}, raw
// barriers between.  Loads lead their LDS write by 1 tile and their use by
// 2 tiles (~8 phases ~ HBM latency).  XCD-grouped grid 1248 = 8x52x3.
// ---------------------------------------------------------------------------
__global__ __launch_bounds__(512, 2) void gemm_f32a(
    const float* __restrict__ A, const unsigned short* __restrict__ B,
    const float* __restrict__ biasBase, unsigned short* __restrict__ C,
    long aLS, long bLS, int biasLS, long cLayerOff, long cRowStride)
{
    __shared__ __align__(16) unsigned short lsA[3][256 * 40];
    __shared__ __align__(16) unsigned short lsB[3][256 * 40];

    const int bid = blockIdx.x;
    const int xcd = bid & 7, slot = bid >> 3;        // 156 slots per XCD
    const int grp = xcd * 52 + slot / 3;             // 0..415
    const int nx  = slot % 3;
    const int l   = grp >> 5;                        // layer 0..12
    const long m0 = (long)(grp & 31) * 256;
    const long n0 = (long)nx * 256;

    const int t = threadIdx.x, lane = t & 63, wave = t >> 6;

    const float* Ab = A + (size_t)l * aLS;
    const unsigned short* Bb = B + (size_t)l * bLS;
    const float* bias = biasBase + (size_t)l * biasLS;

    // staging: thread covers row t>>1 (0..255), k-half t&1 (16 elems)
    const int sRow  = t >> 1;
    const int sHalf = t & 1;
    const float* aSrc = Ab + (m0 + sRow) * (size_t)768 + sHalf * 16;
    const unsigned short* bSrc = Bb + (n0 + sRow) * (size_t)768 + sHalf * 16;

    const int wm = (wave >> 2) * 128;    // 2 M-wave groups
    const int wn = (wave & 3) * 64;      // 4 N-wave groups
    const int lr = lane & 15;
    const int g4 = lane >> 4;
    const int kg = g4 * 8;

    f32x4 acc[8][4];
#pragma unroll
    for (int i = 0; i < 8; i++)
#pragma unroll
        for (int j = 0; j < 4; j++) acc[i][j] = (f32x4){0.f, 0.f, 0.f, 0.f};

    f32x4 ra0[4], ra1[4];
    short8 rb0[2], rb1[2];

#define LOADA(R, K0) { _Pragma("unroll") \
    for (int i_ = 0; i_ < 4; i_++) (R)[i_] = *(const f32x4*)(aSrc + (K0) + i_ * 4); }
#define LOADB(R, K0) { _Pragma("unroll") \
    for (int j_ = 0; j_ < 2; j_++) (R)[j_] = *(const short8*)(bSrc + (K0) + j_ * 8); }
#define WRITEA(R, BUF) { unsigned short* la_ = lsA[BUF]; \
    uint4 w0_, w1_; \
    w0_.x = cvtpk((R)[0][0], (R)[0][1]); w0_.y = cvtpk((R)[0][2], (R)[0][3]); \
    w0_.z = cvtpk((R)[1][0], (R)[1][1]); w0_.w = cvtpk((R)[1][2], (R)[1][3]); \
    w1_.x = cvtpk((R)[2][0], (R)[2][1]); w1_.y = cvtpk((R)[2][2], (R)[2][3]); \
    w1_.z = cvtpk((R)[3][0], (R)[3][1]); w1_.w = cvtpk((R)[3][2], (R)[3][3]); \
    *(uint4*)&la_[sRow * 40 + sHalf * 16]     = w0_; \
    *(uint4*)&la_[sRow * 40 + sHalf * 16 + 8] = w1_; }
#define WRITEB(R, BUF) { unsigned short* lb_ = lsB[BUF]; \
    *(short8*)&lb_[sRow * 40 + sHalf * 16]     = (R)[0]; \
    *(short8*)&lb_[sRow * 40 + sHalf * 16 + 8] = (R)[1]; }

#define MF8(PA, BV, Q) { \
    short8 a0_ = *(const short8*)&(PA)[(wm + (2*(Q)) * 16 + lr) * 40 + kg]; \
    short8 a1_ = *(const short8*)&(PA)[(wm + (2*(Q)+1) * 16 + lr) * 40 + kg]; \
    __builtin_amdgcn_s_setprio(1); \
    _Pragma("unroll") \
    for (int ni_ = 0; ni_ < 4; ni_++) \
        acc[2*(Q)][ni_] = __builtin_amdgcn_mfma_f32_16x16x32_bf16( \
            a0_, (BV)[ni_], acc[2*(Q)][ni_], 0, 0, 0); \
    _Pragma("unroll") \
    for (int ni_ = 0; ni_ < 4; ni_++) \
        acc[2*(Q)+1][ni_] = __builtin_amdgcn_mfma_f32_16x16x32_bf16( \
            a1_, (BV)[ni_], acc[2*(Q)+1][ni_], 0, 0, 0); \
    __builtin_amdgcn_s_setprio(0); }

#define TILE(KS, RLA, RLB, RWA, RWB, DOL, DOW) { \
    const unsigned short* pa_ = lsA[(KS) % 3]; \
    const unsigned short* pb_ = lsB[(KS) % 3]; \
    short8 bv_[4]; \
    if (DOL) LOADA(RLA, ((KS) + 2) * 32); \
    _Pragma("unroll") \
    for (int ni_ = 0; ni_ < 4; ni_++) \
        bv_[ni_] = *(const short8*)&pb_[(wn + ni_ * 16 + lr) * 40 + kg]; \
    MF8(pa_, bv_, 0); PHB; \
    if (DOL) LOADB(RLB, ((KS) + 2) * 32); \
    MF8(pa_, bv_, 1); PHB; \
    if (DOW) { WRITEA(RWA, ((KS) + 1) % 3); WRITEB(RWB, ((KS) + 1) % 3); } \
    MF8(pa_, bv_, 2); PHB; \
    MF8(pa_, bv_, 3); \
    asm volatile("s_waitcnt lgkmcnt(0)" ::: "memory"); PHB; }

    // Prologue: tile0 -> regs -> LDS buf0; tile1 -> regs (pending, written
    // at tile0's P2).  Compiler inserts the vmcnt waits for the reg reads.
    LOADA(ra0, 0);  LOADB(rb0, 0);
    LOADA(ra1, 32); LOADB(rb1, 32);
    WRITEA(ra0, 0); WRITEB(rb0, 0);
    __syncthreads();

    // Steady: tile t computes buf[t%3]; loads tile t+2 into regs[t&1];
    // writes tile t+1 (regs[(t+1)&1]) into buf[(t+1)%3] at P2.
    for (int tp = 0; tp < 20; tp += 2) {
        TILE(tp,     ra0, rb0, ra1, rb1, 1, 1);
        TILE(tp + 1, ra1, rb1, ra0, rb0, 1, 1);
    }
    TILE(20, ra0, rb0, ra1, rb1, 1, 1);
    TILE(21, ra1, rb1, ra0, rb0, 1, 1);
    TILE(22, ra0, rb0, ra1, rb1, 0, 1);   // writes tile 23 (loaded at t=21)
    TILE(23, ra1, rb1, ra0, rb0, 0, 0);

#undef TILE
#undef MF8
#undef WRITEB
#undef WRITEA
#undef LOADB
#undef LOADA

#pragma unroll
    for (int ni = 0; ni < 4; ni++) {
        long col = n0 + wn + ni * 16 + lr;
        float bvs = bias[col];
#pragma unroll
        for (int mi = 0; mi < 8; mi++) {
#pragma unroll
            for (int r = 0; r < 4; r++) {
                long grow = m0 + wm + mi * 16 + g4 * 4 + r;
                size_t coff = (size_t)grow * cRowStride + (size_t)l * cLayerOff + col;
                C[coff] = f2bf(acc[mi][ni][r] + bvs);
            }
        }
    }
}

// ---------------------------------------------------------------------------
// GEMM2: C(f32) = A(bf16) * B(bf16)^T + bias.  64x128 tile, BK=32, gload
// staging + XOR swizzle (R6/R10-verified), grid 768 = 8 x 16 x 6.
// ---------------------------------------------------------------------------
__global__ __launch_bounds__(256) void gemm_bf16_nt(
    const unsigned short* __restrict__ A, const unsigned short* __restrict__ B,
    const float* __restrict__ bias, float* __restrict__ C,
    int K, long cRowStride)
{
    __shared__ __align__(16) unsigned short lsA[2][64 * 32];
    __shared__ __align__(16) unsigned short lsB[2][128 * 32];

    const int bid = blockIdx.x;
    const int xcd = bid & 7, slot = bid >> 3;        // 96 slots per XCD
    const int grp = xcd * 16 + slot / 6;             // 0..127 m-blocks
    const int nx  = slot % 6;
    const long m0 = (long)grp * 64;
    const long n0 = (long)nx * 128;

    const int t = threadIdx.x, lane = t & 63, wave = t >> 6;

    const int srow = wave * 16 + (lane >> 2);        // 0..63
    const int schk = (lane & 3) ^ ((lane >> 3) & 3);
    const int dS   = wave * 1024 + lane * 16;

    const int wm = (wave >> 1) * 32;
    const int wn = (wave & 1) * 64;
    const int lr = lane & 15;
    const int g4 = lane >> 4;
    const int kg = g4 * 8;
    const int swz = ((lr >> 1) & 3) * 8;

    const unsigned short* aSp  = A + (m0 + srow) * (size_t)K + schk * 8;
    const unsigned short* bSp0 = B + (n0 + srow) * (size_t)K + schk * 8;
    const unsigned short* bSp1 = B + (n0 + 64 + srow) * (size_t)K + schk * 8;

    f32x4 acc[2][4];
#pragma unroll
    for (int i = 0; i < 2; i++)
#pragma unroll
        for (int j = 0; j < 4; j++) acc[i][j] = (f32x4){0.f, 0.f, 0.f, 0.f};

    auto STAGE = [&](int buf, int k0) {
        char* la = (char*)lsA[buf];
        char* lb = (char*)lsB[buf];
        gload16(aSp + k0, la + dS);
        gload16(bSp0 + k0, lb + dS);
        gload16(bSp1 + k0, lb + 4096 + dS);
    };
    auto COMP = [&](int buf) {
        short8 af[2], bv[4];
        const unsigned short* pa = lsA[buf];
        const unsigned short* pb = lsB[buf];
#pragma unroll
        for (int mi = 0; mi < 2; mi++)
            af[mi] = *(const short8*)&pa[(wm + mi * 16 + lr) * 32 + (kg ^ swz)];
#pragma unroll
        for (int ni = 0; ni < 4; ni++)
            bv[ni] = *(const short8*)&pb[(wn + ni * 16 + lr) * 32 + (kg ^ swz)];
#pragma unroll
        for (int mi = 0; mi < 2; mi++)
#pragma unroll
            for (int ni = 0; ni < 4; ni++)
                acc[mi][ni] = __builtin_amdgcn_mfma_f32_16x16x32_bf16(
                    af[mi], bv[ni], acc[mi][ni], 0, 0, 0);
    };

    STAGE(0, 0);
    __syncthreads();
    int cur = 0;
    const int nst = K >> 5;
    for (int ks = 1; ks < nst; ks++) {
        STAGE(cur ^ 1, ks * 32);
        COMP(cur);
        __syncthreads();
        cur ^= 1;
    }
    COMP(cur);

#pragma unroll
    for (int ni = 0; ni < 4; ni++) {
        long col = n0 + wn + ni * 16 + lr;
        float bvs = bias[col];
#pragma unroll
        for (int mi = 0; mi < 2; mi++) {
#pragma unroll
            for (int r = 0; r < 4; r++) {
                long grow = m0 + wm + mi * 16 + g4 * 4 + r;
                C[(size_t)grow * cRowStride + col] = acc[mi][ni][r] + bvs;
            }
        }
    }
}

// ---------------------------------------------------------------------------
// Fold kvln gamma into k_w; compute s_k = sum(kw*g), c_k = kw.b + k_bias.
// ---------------------------------------------------------------------------
__global__ __launch_bounds__(256) void wtrans(
    const float* __restrict__ kw, const float* __restrict__ kvg,
    const float* __restrict__ kvb, const float* __restrict__ kbias,
    float* __restrict__ kwp, float* __restrict__ skv, float* __restrict__ ckv)
{
    __shared__ float red[8];
    const int q = blockIdx.x, t = threadIdx.x;
    const int lane = t & 63, wave = t >> 6;
    float s = 0.f, c = 0.f;
    for (int v = t; v < 768; v += 256) {
        float w = kw[q * 768 + v];
        float wp = w * kvg[v];
        kwp[q * 768 + v] = wp;
        s += wp;
        c += w * kvb[v];
    }
#pragma unroll
    for (int off = 1; off < 64; off <<= 1) {
        s += __shfl_xor(s, off);
        c += __shfl_xor(c, off);
    }
    if (lane == 0) { red[wave] = s; red[4 + wave] = c; }
    __syncthreads();
    if (t == 0) {
        skv[q] = red[0] + red[1] + red[2] + red[3];
        ckv[q] = red[4] + red[5] + red[6] + red[7] + kbias[q];
    }
}

// ---------------------------------------------------------------------------
// LayerNorm rows of 768 (fp32 src) -> bf16.  Q side only.
// ---------------------------------------------------------------------------
__global__ __launch_bounds__(256) void ln_rows_f32(
    const float* __restrict__ src, unsigned short* __restrict__ dst,
    const float* __restrict__ gam, const float* __restrict__ bet)
{
    const int lane = threadIdx.x & 63;
    const int wave = threadIdx.x >> 6;
    const size_t row = (size_t)blockIdx.x * 4 + wave;

    float x[3][4];
    float s = 0.f, sq = 0.f;
#pragma unroll
    for (int i = 0; i < 3; i++) {
        int v = i * 256 + lane * 4;
        float4 f = *(const float4*)(src + row * 768 + v);
        x[i][0] = f.x; x[i][1] = f.y; x[i][2] = f.z; x[i][3] = f.w;
#pragma unroll
        for (int e = 0; e < 4; e++) { s += x[i][e]; sq += x[i][e] * x[i][e]; }
    }
#pragma unroll
    for (int off = 1; off < 64; off <<= 1) {
        s  += __shfl_xor(s, off);
        sq += __shfl_xor(sq, off);
    }
    float mean = s * (1.f / 768.f);
    float var  = sq * (1.f / 768.f) - mean * mean;
    float rs   = rsqrtf(var + 1e-5f);
#pragma unroll
    for (int i = 0; i < 3; i++) {
        int v = i * 256 + lane * 4;
        float4 gg = *(const float4*)(gam + v);
        float4 bb = *(const float4*)(bet + v);
        ushort4 o;
        o.x = f2bf((x[i][0] - mean) * rs * gg.x + bb.x);
        o.y = f2bf((x[i][1] - mean) * rs * gg.y + bb.y);
        o.z = f2bf((x[i][2] - mean) * rs * gg.z + bb.z);
        o.w = f2bf((x[i][3] - mean) * rs * gg.w + bb.w);
        *(ushort4*)(dst + row * 768 + v) = o;
    }
}

// ---------------------------------------------------------------------------
// proj32: out[M][32] = A[M][768](bf16) @ W[32][768](f32)^T + bias (plain).
// ---------------------------------------------------------------------------
__global__ __launch_bounds__(256) void proj32(
    const unsigned short* __restrict__ A, const float* __restrict__ W,
    const float* __restrict__ bias, unsigned short* __restrict__ out)
{
    __shared__ __align__(16) unsigned short lsW[32 * 776];
    __shared__ __align__(16) unsigned short lsA[128 * 40];
    const int t = threadIdx.x;

#pragma unroll
    for (int i = 0; i < 24; i++) {
        int fi = t + i * 256;
        int row = fi / 192;
        int c4  = fi % 192;
        float4 f = *(const float4*)(W + row * 768 + c4 * 4);
        ushort4 u;
        u.x = f2bf(f.x); u.y = f2bf(f.y); u.z = f2bf(f.z); u.w = f2bf(f.w);
        *(ushort4*)&lsW[row * 776 + c4 * 4] = u;
    }

    const size_t m0 = (size_t)blockIdx.x * 128;
    const int lane = t & 63, wave = t >> 6;
    const int wm = wave * 32;
    const int lr = lane & 15, kg = (lane >> 4) * 8;
    const int row_s = t >> 3, c4s = t & 7;

    f32x4 acc[2][2];
#pragma unroll
    for (int i = 0; i < 2; i++)
#pragma unroll
        for (int j = 0; j < 2; j++) acc[i][j] = (f32x4){0.f, 0.f, 0.f, 0.f};

    __syncthreads();

    for (int k0 = 0; k0 < 768; k0 += 32) {
#pragma unroll
        for (int i = 0; i < 4; i++) {
            int row = row_s + 32 * i;
            ushort4 v = *(const ushort4*)(A + (m0 + row) * 768 + k0 + c4s * 4);
            *(ushort4*)&lsA[row * 40 + c4s * 4] = v;
        }
        __syncthreads();
        short8 af[2], bw[2];
#pragma unroll
        for (int mi = 0; mi < 2; mi++)
            af[mi] = *(const short8*)&lsA[(wm + mi * 16 + lr) * 40 + kg];
#pragma unroll
        for (int ni = 0; ni < 2; ni++)
            bw[ni] = *(const short8*)&lsW[(ni * 16 + lr) * 776 + k0 + kg];
#pragma unroll
        for (int mi = 0; mi < 2; mi++)
#pragma unroll
            for (int ni = 0; ni < 2; ni++)
                acc[mi][ni] = __builtin_amdgcn_mfma_f32_16x16x32_bf16(
                    af[mi], bw[ni], acc[mi][ni], 0, 0, 0);
        __syncthreads();
    }

#pragma unroll
    for (int ni = 0; ni < 2; ni++) {
        int col = ni * 16 + lr;
        float bv = bias[col];
#pragma unroll
        for (int mi = 0; mi < 2; mi++) {
#pragma unroll
            for (int r = 0; r < 4; r++) {
                size_t grow = m0 + wm + mi * 16 + (lane >> 4) * 4 + r;
                out[grow * 32 + col] = f2bf(acc[mi][ni][r] + bv);
            }
        }
    }
}

// ---------------------------------------------------------------------------
// proj32k_stats: k = rs*(dot(x_raw, kwp) - mean*s_k) + c_k, with row stats
// computed in the K-loop.
// ---------------------------------------------------------------------------
__global__ __launch_bounds__(256) void proj32k_stats(
    const unsigned short* __restrict__ A, const float* __restrict__ W,
    const float* __restrict__ skv, const float* __restrict__ ckv,
    unsigned short* __restrict__ out, float2* __restrict__ st)
{
    __shared__ __align__(16) unsigned short lsW[32 * 776];
    __shared__ __align__(16) unsigned short lsA[128 * 40];
    __shared__ float2 lstat[128];
    const int t = threadIdx.x;

#pragma unroll
    for (int i = 0; i < 24; i++) {
        int fi = t + i * 256;
        int row = fi / 192;
        int c4  = fi % 192;
        float4 f = *(const float4*)(W + row * 768 + c4 * 4);
        ushort4 u;
        u.x = f2bf(f.x); u.y = f2bf(f.y); u.z = f2bf(f.z); u.w = f2bf(f.w);
        *(ushort4*)&lsW[row * 776 + c4 * 4] = u;
    }

    const size_t m0 = (size_t)blockIdx.x * 128;
    const int lane = t & 63, wave = t >> 6;
    const int wm = wave * 32;
    const int lr = lane & 15, kg = (lane >> 4) * 8;
    const int row_s = t >> 3, c4s = t & 7;

    f32x4 acc[2][2];
#pragma unroll
    for (int i = 0; i < 2; i++)
#pragma unroll
        for (int j = 0; j < 2; j++) acc[i][j] = (f32x4){0.f, 0.f, 0.f, 0.f};

    float s_[4] = {0.f, 0.f, 0.f, 0.f}, sq_[4] = {0.f, 0.f, 0.f, 0.f};

    __syncthreads();

    for (int k0 = 0; k0 < 768; k0 += 32) {
#pragma unroll
        for (int i = 0; i < 4; i++) {
            int row = row_s + 32 * i;
            ushort4 v = *(const ushort4*)(A + (m0 + row) * 768 + k0 + c4s * 4);
            *(ushort4*)&lsA[row * 40 + c4s * 4] = v;
            float x0 = bf2f(v.x), x1 = bf2f(v.y), x2 = bf2f(v.z), x3 = bf2f(v.w);
            s_[i]  += x0 + x1 + x2 + x3;
            sq_[i] += x0 * x0 + x1 * x1 + x2 * x2 + x3 * x3;
        }
        __syncthreads();
        short8 af[2], bw[2];
#pragma unroll
        for (int mi = 0; mi < 2; mi++)
            af[mi] = *(const short8*)&lsA[(wm + mi * 16 + lr) * 40 + kg];
#pragma unroll
        for (int ni = 0; ni < 2; ni++)
            bw[ni] = *(const short8*)&lsW[(ni * 16 + lr) * 776 + k0 + kg];
#pragma unroll
        for (int mi = 0; mi < 2; mi++)
#pragma unroll
            for (int ni = 0; ni < 2; ni++)
                acc[mi][ni] = __builtin_amdgcn_mfma_f32_16x16x32_bf16(
                    af[mi], bw[ni], acc[mi][ni], 0, 0, 0);
        __syncthreads();
    }

#pragma unroll
    for (int i = 0; i < 4; i++) {
#pragma unroll
        for (int off = 1; off < 8; off <<= 1) {
            s_[i]  += __shfl_xor(s_[i], off);
            sq_[i] += __shfl_xor(sq_[i], off);
        }
    }
    if (c4s == 0) {
#pragma unroll
        for (int i = 0; i < 4; i++) {
            int row = row_s + 32 * i;
            float mean = s_[i] * (1.f / 768.f);
            float var  = sq_[i] * (1.f / 768.f) - mean * mean;
            float2 sv = make_float2(mean, rsqrtf(var + 1e-5f));
            lstat[row] = sv;
            st[m0 + row] = sv;
        }
    }
    __syncthreads();

#pragma unroll
    for (int ni = 0; ni < 2; ni++) {
        int col = ni * 16 + lr;
        float sk = skv[col], ck = ckv[col];
#pragma unroll
        for (int mi = 0; mi < 2; mi++) {
#pragma unroll
            for (int r = 0; r < 4; r++) {
                int lrow = wm + mi * 16 + (lane >> 4) * 4 + r;
                float2 s2 = lstat[lrow];
                out[(m0 + lrow) * 32 + col] =
                    f2bf(s2.y * (acc[mi][ni][r] - s2.x * sk) + ck);
            }
        }
    }
}

// ---------------------------------------------------------------------------
// Attention on RAW aligned values with LN folded in.  One wave per token.
// ---------------------------------------------------------------------------
__global__ __launch_bounds__(256) void attn2(
    const unsigned short* __restrict__ qb, const unsigned short* __restrict__ kb,
    const unsigned short* __restrict__ kv, const float2* __restrict__ st,
    const float* __restrict__ gv, const float* __restrict__ bvv,
    unsigned short* __restrict__ oh)
{
    __shared__ float lat[4][4][13];
    __shared__ float latc[4][4];
    const int t = threadIdx.x, lane = t & 63, wave = t >> 6;
    const size_t m = (size_t)blockIdx.x * 4 + wave;

    if (lane < 32) {
        int j = lane;
        float qv = bf2f(qb[m * 32 + j]);
        float p[13];
#pragma unroll
        for (int l = 0; l < 13; l++)
            p[l] = qv * bf2f(kb[(m * 13 + l) * 32 + j]);
#pragma unroll
        for (int off = 1; off < 8; off <<= 1)
#pragma unroll
            for (int l = 0; l < 13; l++) p[l] += __shfl_xor(p[l], off);

        const float sc = 0.17677669529663687f; // 1 / (sqrt(8) * 2)
        float mx = -1e30f;
#pragma unroll
        for (int l = 0; l < 13; l++) { p[l] *= sc; mx = fmaxf(mx, p[l]); }
        float se = 0.f;
#pragma unroll
        for (int l = 0; l < 13; l++) { p[l] = __expf(p[l] - mx); se += p[l]; }
        float inv = 1.f / se;
        if ((j & 7) == 0) {
            int h = j >> 3;
            float corr = 0.f;
#pragma unroll
            for (int l = 0; l < 13; l++) {
                float2 s_ = st[m * 13 + l];
                float wl = p[l] * inv * s_.y;
                lat[wave][h][l] = wl;
                corr += wl * s_.x;
            }
            latc[wave][h] = corr;
        }
    }
    __syncthreads();

    f32x4 g4v[3], b4[3];
#pragma unroll
    for (int i = 0; i < 3; i++) {
        g4v[i] = *(const f32x4*)(gv + i * 256 + lane * 4);
        b4[i] = *(const f32x4*)(bvv + i * 256 + lane * 4);
    }

    float acc[4][3][4];
#pragma unroll
    for (int h = 0; h < 4; h++)
#pragma unroll
        for (int i = 0; i < 3; i++)
#pragma unroll
            for (int e = 0; e < 4; e++) acc[h][i][e] = 0.f;

    for (int l = 0; l < 13; l++) {
        float al[4];
#pragma unroll
        for (int h = 0; h < 4; h++) al[h] = lat[wave][h][l];
#pragma unroll
        for (int i = 0; i < 3; i++) {
            ushort4 u = *(const ushort4*)(kv + (m * 13 + l) * 768 + i * 256 + lane * 4);
            float xv[4] = {bf2f(u.x), bf2f(u.y), bf2f(u.z), bf2f(u.w)};
#pragma unroll
            for (int h = 0; h < 4; h++)
#pragma unroll
                for (int e = 0; e < 4; e++) acc[h][i][e] += al[h] * xv[e];
        }
    }
#pragma unroll
    for (int h = 0; h < 4; h++) {
        float ch = latc[wave][h];
#pragma unroll
        for (int i = 0; i < 3; i++) {
            ushort4 o;
            o.x = f2bf(g4v[i][0] * (acc[h][i][0] - ch) + b4[i][0]);
            o.y = f2bf(g4v[i][1] * (acc[h][i][1] - ch) + b4[i][1]);
            o.z = f2bf(g4v[i][2] * (acc[h][i][2] - ch) + b4[i][2]);
            o.w = f2bf(g4v[i][3] * (acc[h][i][3] - ch) + b4[i][3]);
            *(ushort4*)(oh + m * 3072 + h * 768 + i * 256 + lane * 4) = o;
        }
    }
}

// ---------------------------------------------------------------------------
extern "C" void kernel_launch(void* const* d_in, const int* in_sizes, int n_in,
                              void* d_out, int out_size, void* d_ws, size_t ws_size,
                              hipStream_t stream) {
    const float* base  = (const float*)d_in[0];
    const float* reps  = (const float*)d_in[1];
    const float* aw    = (const float*)d_in[2];
    const float* ab    = (const float*)d_in[3];
    const float* qg    = (const float*)d_in[4];
    const float* qbeta = (const float*)d_in[5];
    const float* kvg   = (const float*)d_in[6];
    const float* kvb   = (const float*)d_in[7];
    const float* qw    = (const float*)d_in[8];
    const float* qbias = (const float*)d_in[9];
    const float* kw    = (const float*)d_in[10];
    const float* kbias = (const float*)d_in[11];
    const float* ow    = (const float*)d_in[12];
    const float* obias = (const float*)d_in[13];
    float* out = (float*)d_out;

    float2* stats = (float2*)d_ws;                              // [MROWS]
    float* kwp = (float*)(stats + MROWS);                       // [32][768]
    float* skv = kwp + 32 * 768;                                // [32]
    float* ckv = skv + 32;                                      // [32]
    unsigned short* aligned = (unsigned short*)(ckv + 32);      // [MROWS][768]
    unsigned short* UNION = aligned + (size_t)MROWS * 768;      // awb -> Qn -> oh
    unsigned short* kbuf = UNION + (size_t)MTOK * 3072;         // [MROWS][32]
    unsigned short* qbuf = kbuf + (size_t)MROWS * 32;           // [MTOK][32]
    unsigned short* owb  = qbuf + (size_t)MTOK * 32;            // [768][3072]

    unsigned short* awb = UNION;

    // 0. weight conversions + LN folding precompute
    {
        long n = (long)NL * 768 * 768;
        conv_f32_bf16<<<(int)(n / 8 / 256), 256, 0, stream>>>(aw, awb, n);
        long n2 = (long)768 * 3072;
        conv_f32_bf16<<<(int)(n2 / 8 / 256), 256, 0, stream>>>(ow, owb, n2);
        wtrans<<<32, 256, 0, stream>>>(kw, kvg, kvb, kbias, kwp, skv, ckv);
    }

    // 1. aligner GEMM: 256^2, 8 waves, 3-buffer 2-tile-deep pipeline
    gemm_f32a<<<1248, 512, 0, stream>>>(
        reps, awb, ab, aligned,
        (long)MTOK * 768, (long)768 * 768, 768,
        768L, (long)NL * 768);

    // 2. k projection + fused row stats
    proj32k_stats<<<MROWS / 128, 256, 0, stream>>>(
        aligned, kwp, skv, ckv, kbuf, stats);

    // 3. q side: LN(base) -> Qn, then proj32 (awb dead, reuse UNION)
    unsigned short* Qn = UNION;
    ln_rows_f32<<<MTOK / 4, 256, 0, stream>>>(base, Qn, qg, qbeta);
    proj32<<<MTOK / 128, 256, 0, stream>>>(Qn, qw, qbias, qbuf);

    // 4. attention on raw aligned (Qn dead, reuse UNION for oh)
    unsigned short* oh = UNION;
    attn2<<<MTOK / 4, 256, 0, stream>>>(qbuf, kbuf, aligned, stats, kvg, kvb, oh);

    // 5. out = out_heads @ out_w^T + out_b (64x128 tiles, 768 blocks)
    gemm_bf16_nt<<<768, 256, 0, stream>>>(oh, owb, obias, out, 3072, 768L);
}